// Round 3
// baseline (189.655 us; speedup 1.0000x reference)
//
#include <hip/hip_runtime.h>
#include <hip/hip_fp16.h>
#include <cmath>

#define N_NODES 50000
#define N_EDGES 800000
#define D 64
#define N_REL 8

#define NODES_PER_BLK 32
#define TN 16                       // nodes per block in tables_kernel
#define CPAD 16                     // cnt stride in ints: 64B line per counter
#define MAXDEG 64                   // ELL row pad; P(deg>64 | Poisson(16)) ~ 1e-20
#define NSEG 8                      // dst segments == XCD count
#define SEG_DIV 6250                // 50000 / 8

// float -> bf16 bits, round-to-nearest-even
static __device__ __forceinline__ unsigned f2bf(float f) {
    unsigned u = __float_as_uint(f);
    return (u + 0x7FFFu + ((u >> 16) & 1u)) >> 16;
}
#define BFLO(u) __uint_as_float((u) << 16)
#define BFHI(u) __uint_as_float((u) & 0xFFFF0000u)

// ---------------------------------------------------------------------------
// K0: w[r*128 + j] = sum_k W_r[r][j][k]  + zero the padded cnt array
// ---------------------------------------------------------------------------
__global__ void wprep_kernel(const float* __restrict__ W_r, float* __restrict__ w,
                             int* __restrict__ cnt) {
    int t = blockIdx.x * blockDim.x + threadIdx.x;
    if (t < N_REL * 2 * D) {
        const float* p = W_r + (size_t)t * D;
        float s = 0.0f;
#pragma unroll
        for (int k = 0; k < D; ++k) s += p[k];
        w[t] = s;
    }
    for (int i = t; i < N_NODES * CPAD; i += gridDim.x * blockDim.x)
        cnt[i] = 0;
}

// ---------------------------------------------------------------------------
// K1: logit tables (tall-skinny GEMM) + xb side-product (packed bf16 x).
// ---------------------------------------------------------------------------
__global__ __launch_bounds__(256) void tables_kernel(
    const float* __restrict__ x, const float* __restrict__ w,
    float* __restrict__ Dn, float* __restrict__ Sr,
    unsigned short* __restrict__ xb)
{
    __shared__ float xs[TN][68];
    __shared__ float ws[16][68];

    int tid = threadIdx.x;
    int n0  = blockIdx.x * TN;

    for (int i = tid; i < 16 * 64; i += 256)
        ws[i >> 6][i & 63] = w[i];
    for (int i = tid; i < TN * 64; i += 256) {
        int n = n0 + (i >> 6);
        xs[i >> 6][i & 63] = (n < N_NODES) ? x[(size_t)n * D + (i & 63)] : 0.f;
    }
    __syncthreads();

    for (int i = tid; i < TN * 64; i += 256) {
        int n = n0 + (i >> 6);
        if (n < N_NODES) xb[(size_t)n0 * D + i] = (unsigned short)f2bf(xs[i >> 6][i & 63]);
    }

    int q = tid & 15, nl = tid >> 4;
    float acc = 0.f;
#pragma unroll
    for (int k = 0; k < 64; k += 4) {
        float4 a = *(const float4*)&xs[nl][k];
        float4 b = *(const float4*)&ws[q][k];
        acc += a.x * b.x + a.y * b.y + a.z * b.z + a.w * b.w;
    }
    int n = n0 + nl;
    if (n < N_NODES) {
        int r = q >> 1;
        if ((q & 1) == 0) Dn[n * 8 + r] = acc;
        else              Sr[n * 8 + r] = acc;
    }
}

// ---------------------------------------------------------------------------
// K2: XCD-partitioned ELL scatter, 1 edge/thread (R2 structure, confirmed).
//
// R3 change: dst/src/rel loads are NONTEMPORAL (evict-first). Accounting of
// R2's 97MB HBM traffic says ~75MB is epack line churn: only ~5MB of lines
// are touched but each is fetched/evicted/refetched ~7x because the 9.6MB
// read-once edge stream flushes the owning XCD's 1.6MB epack slice out of
// its 4MB L2. nt on the stream leaves the scatter lines resident so the
// 16 slot-writes per line combine before writeback.
// ---------------------------------------------------------------------------
__global__ __launch_bounds__(256) void scatter_kernel(
    const int* __restrict__ src, const int* __restrict__ dst,
    const int* __restrict__ rel,
    int* __restrict__ cnt,
    const float* __restrict__ Dn, const float* __restrict__ Sr,
    unsigned int* __restrict__ epack) {
    int seg   = blockIdx.x & (NSEG - 1);
    int chunk = blockIdx.x >> 3;
    int e = chunk * 256 + threadIdx.x;
    if (e >= N_EDGES) return;

    // issue all three coalesced loads before any dependent use (evict-first)
    int d = __builtin_nontemporal_load(dst + e);
    int s = __builtin_nontemporal_load(src + e);
    int r = __builtin_nontemporal_load(rel + e);
    // pin: forbid sinking src/rel loads into the survivor branch
    asm volatile("" :: "v"(d), "v"(s), "v"(r));

    if ((unsigned)d / SEG_DIV != (unsigned)seg) return;   // magic-mul div

    // rank is independent of gate: issue the atomic first, overlap gathers
    int rank = atomicAdd(&cnt[d * CPAD], 1);

    float logit = Dn[d * 8 + r] + Sr[s * 8 + r];
    float gate = 1.0f / (1.0f + __expf(-logit));
    if (rank < MAXDEG) {
        unsigned pv = ((unsigned)__half_as_ushort(__float2half_rn(gate)) << 16)
                    | (unsigned)s;
        epack[(size_t)d * MAXDEG + rank] = pv;
    }
}

// ---------------------------------------------------------------------------
// K3: aggregation over ELL rows.
//
// R3 rewrite: the whole ELL row (<=64 slots) is exactly one lane-coalesced
// wave load -- lane l takes slot l -- then (gate,src) are distributed by
// __shfl. This removes the per-iteration epack load from the dependence
// chain: iterations' xb gathers are now fully independent (wave-level MLP)
// and all branches vanish (pad slots carry gate=0/src=0, contribute 0).
// ---------------------------------------------------------------------------
__global__ __launch_bounds__(256) void agg_kernel(
    const unsigned short* __restrict__ xb,
    const int*   __restrict__ cnt,
    const unsigned int* __restrict__ epack,
    unsigned int* __restrict__ aggb)   // (N_NODES, 32) packed bf16 pairs
{
    int n    = (blockIdx.x * blockDim.x + threadIdx.x) >> 6;
    int lane = threadIdx.x & 63;
    if (n >= N_NODES) return;

    int deg = cnt[n * CPAD];
    int m   = (deg < MAXDEG) ? deg : MAXDEG;

    // one coalesced read of the whole ELL row: lane l <- slot l
    unsigned ev = 0u;
    if (lane < m) ev = epack[(size_t)n * MAXDEG + lane];
    float gl = __half2float(__ushort_as_half((unsigned short)(ev >> 16)));
    int   ol = (int)(ev & 0xFFFFu) * D;   // element offset of src row

    int sub = lane >> 4;      // edge slot group 0..3
    int q4  = (lane & 15) * 4; // dims q4..q4+3

    float ax = 0.f, ay = 0.f, az = 0.f, aw = 0.f;

    for (int base = 0; base < m; base += 8) {
        int e0 = base + sub;
        int e1 = base + 4 + sub;
        float g0 = __shfl(gl, e0, 64);
        int   o0 = __shfl(ol, e0, 64);
        float g1 = __shfl(gl, e1, 64);
        int   o1 = __shfl(ol, e1, 64);
        uint2 u0 = *(const uint2*)&xb[(size_t)o0 + q4];
        uint2 u1 = *(const uint2*)&xb[(size_t)o1 + q4];
        ax += g0 * BFLO(u0.x) + g1 * BFLO(u1.x);
        ay += g0 * BFHI(u0.x) + g1 * BFHI(u1.x);
        az += g0 * BFLO(u0.y) + g1 * BFLO(u1.y);
        aw += g0 * BFHI(u0.y) + g1 * BFHI(u1.y);
    }

#pragma unroll
    for (int off = 16; off <= 32; off <<= 1) {
        ax += __shfl_xor(ax, off, 64);
        ay += __shfl_xor(ay, off, 64);
        az += __shfl_xor(az, off, 64);
        aw += __shfl_xor(aw, off, 64);
    }

    if (sub == 0) {
        float inv = 1.0f / fmaxf((float)deg, 1.0f);   // normalize by TRUE degree
        uint2 pr;
        pr.x = f2bf(ax * inv) | (f2bf(ay * inv) << 16);
        pr.y = f2bf(az * inv) | (f2bf(aw * inv) << 16);
        *(uint2*)&aggb[(size_t)n * 32 + 2 * (lane & 15)] = pr;
    }
}

// ---------------------------------------------------------------------------
// K4: out = leaky_relu([x, agg] @ W_lin^T + b), all LDS operands bf16-packed.
// ---------------------------------------------------------------------------
__global__ __launch_bounds__(256, 6) void lin_kernel(
    const unsigned int* __restrict__ xbu,   // packed x, 32 uints/node
    const unsigned int* __restrict__ aggb,  // packed agg, 32 uints/node
    const float* __restrict__ W_lin,
    const float* __restrict__ b_lin,
    float* __restrict__ out)
{
    __shared__ unsigned int W2[64][66];
    __shared__ unsigned int c2[NODES_PER_BLK][66];
    __shared__ float b_lds[64];

    int tid = threadIdx.x;
    int n0  = blockIdx.x * NODES_PER_BLK;

    for (int i = tid; i < 64 * 64; i += 256) {
        int j = i >> 6, kp = i & 63;
        float2 wv = *(const float2*)&W_lin[j * 128 + kp * 2];
        W2[j][kp] = f2bf(wv.x) | (f2bf(wv.y) << 16);
    }
    if (tid < 64) b_lds[tid] = b_lin[tid];

    for (int i = tid; i < NODES_PER_BLK * 32; i += 256) {
        int nl = i >> 5, kp = i & 31;
        int n  = n0 + nl;
        unsigned vx = 0u, va = 0u;
        if (n < N_NODES) {
            vx = xbu[(size_t)n * 32 + kp];
            va = aggb[(size_t)n * 32 + kp];
        }
        c2[nl][kp]      = vx;
        c2[nl][32 + kp] = va;
    }
    __syncthreads();

    int tx = tid & 15, ty = tid >> 4;
    float acc[2][4];
#pragma unroll
    for (int i = 0; i < 2; ++i)
#pragma unroll
        for (int jj = 0; jj < 4; ++jj) acc[i][jj] = b_lds[tx + 16 * jj];

#pragma unroll 2
    for (int kp = 0; kp < 64; kp += 2) {      // 2 pairs = 4 dims per iter
        uint2 cu[2], wu[4];
        cu[0] = *(const uint2*)&c2[ty][kp];
        cu[1] = *(const uint2*)&c2[ty + 16][kp];
#pragma unroll
        for (int jj = 0; jj < 4; ++jj)
            wu[jj] = *(const uint2*)&W2[tx + 16 * jj][kp];
#pragma unroll
        for (int i = 0; i < 2; ++i) {
            float cx = BFLO(cu[i].x), cy = BFHI(cu[i].x);
            float cz = BFLO(cu[i].y), cw = BFHI(cu[i].y);
#pragma unroll
            for (int jj = 0; jj < 4; ++jj) {
                acc[i][jj] += cx * BFLO(wu[jj].x) + cy * BFHI(wu[jj].x)
                            + cz * BFLO(wu[jj].y) + cw * BFHI(wu[jj].y);
            }
        }
    }

#pragma unroll
    for (int i = 0; i < 2; ++i) {
        int n = n0 + ty + 16 * i;
        if (n < N_NODES) {
#pragma unroll
            for (int jj = 0; jj < 4; ++jj) {
                float v = acc[i][jj];
                out[(size_t)n * D + tx + 16 * jj] = (v > 0.f) ? v : 0.01f * v;
            }
        }
    }
}

// ---------------------------------------------------------------------------
extern "C" void kernel_launch(void* const* d_in, const int* in_sizes, int n_in,
                              void* d_out, int out_size, void* d_ws, size_t ws_size,
                              hipStream_t stream) {
    const float* x     = (const float*)d_in[0];
    const int*   src   = (const int*)  d_in[1];
    const int*   dst   = (const int*)  d_in[2];
    const int*   rel   = (const int*)  d_in[3];
    const float* W_r   = (const float*)d_in[4];
    const float* W_lin = (const float*)d_in[5];
    const float* b_lin = (const float*)d_in[6];
    float* out = (float*)d_out;

    char* p = (char*)d_ws;
    float*  w       = (float*)p;                p += 4096;
    float*  Dn      = (float*)p;                p += (size_t)N_NODES * 8 * 4;       // 1.6 MB
    float*  Sr      = (float*)p;                p += (size_t)N_NODES * 8 * 4;       // 1.6 MB
    int*    cnt     = (int*)p;                  p += (size_t)N_NODES * CPAD * 4;    // 3.2 MB
    unsigned int* epack = (unsigned int*)p;     p += (size_t)N_NODES * MAXDEG * 4;  // 12.8 MB
    unsigned short* xb = (unsigned short*)p;    p += (size_t)N_NODES * D * 2;       // 6.4 MB
    unsigned int* aggb = (unsigned int*)p;      p += (size_t)N_NODES * 32 * 4;      // 6.4 MB

    wprep_kernel<<<512, 256, 0, stream>>>(W_r, w, cnt);
    tables_kernel<<<(N_NODES + TN - 1) / TN, 256, 0, stream>>>(x, w, Dn, Sr, xb);
    scatter_kernel<<<NSEG * ((N_EDGES + 255) / 256), 256, 0, stream>>>(
        src, dst, rel, cnt, Dn, Sr, epack);
    agg_kernel<<<(N_NODES * 64 + 255) / 256, 256, 0, stream>>>(xb, cnt, epack, aggb);
    lin_kernel<<<(N_NODES + NODES_PER_BLK - 1) / NODES_PER_BLK, 256, 0, stream>>>(
        (const unsigned int*)xb, aggb, W_lin, b_lin, out);
}

// Round 4
// 176.295 us; speedup vs baseline: 1.0758x; 1.0758x over previous
//
#include <hip/hip_runtime.h>
#include <hip/hip_fp16.h>
#include <cmath>

#define N_NODES 50000
#define N_EDGES 800000
#define D 64
#define N_REL 8

#define NODES_PER_BLK 32
#define TN 16                       // nodes per block in tables_kernel
#define MAXDEG 64                   // ELL row pad; P(deg>64 | Poisson(16)) ~ 1e-20
#define NSEG 8                      // dst segments == XCD count
#define SEG_DIV 6250                // 50000 / 8

// float -> bf16 bits, round-to-nearest-even
static __device__ __forceinline__ unsigned f2bf(float f) {
    unsigned u = __float_as_uint(f);
    return (u + 0x7FFFu + ((u >> 16) & 1u)) >> 16;
}
#define BFLO(u) __uint_as_float((u) << 16)
#define BFHI(u) __uint_as_float((u) & 0xFFFF0000u)

// ---------------------------------------------------------------------------
// K0: w[r*128 + j] = sum_k W_r[r][j][k]  + zero the cnt array (200 KB now)
// ---------------------------------------------------------------------------
__global__ void wprep_kernel(const float* __restrict__ W_r, float* __restrict__ w,
                             int* __restrict__ cnt) {
    int t = blockIdx.x * blockDim.x + threadIdx.x;
    if (t < N_REL * 2 * D) {
        const float* p = W_r + (size_t)t * D;
        float s = 0.0f;
#pragma unroll
        for (int k = 0; k < D; ++k) s += p[k];
        w[t] = s;
    }
    for (int i = t; i < N_NODES; i += gridDim.x * blockDim.x)
        cnt[i] = 0;
}

// ---------------------------------------------------------------------------
// K1: logit tables (tall-skinny GEMM) + xb side-product (packed bf16 x).
// ---------------------------------------------------------------------------
__global__ __launch_bounds__(256) void tables_kernel(
    const float* __restrict__ x, const float* __restrict__ w,
    float* __restrict__ Dn, float* __restrict__ Sr,
    unsigned short* __restrict__ xb)
{
    __shared__ float xs[TN][68];
    __shared__ float ws[16][68];

    int tid = threadIdx.x;
    int n0  = blockIdx.x * TN;

    for (int i = tid; i < 16 * 64; i += 256)
        ws[i >> 6][i & 63] = w[i];
    for (int i = tid; i < TN * 64; i += 256) {
        int n = n0 + (i >> 6);
        xs[i >> 6][i & 63] = (n < N_NODES) ? x[(size_t)n * D + (i & 63)] : 0.f;
    }
    __syncthreads();

    for (int i = tid; i < TN * 64; i += 256) {
        int n = n0 + (i >> 6);
        if (n < N_NODES) xb[(size_t)n0 * D + i] = (unsigned short)f2bf(xs[i >> 6][i & 63]);
    }

    int q = tid & 15, nl = tid >> 4;
    float acc = 0.f;
#pragma unroll
    for (int k = 0; k < 64; k += 4) {
        float4 a = *(const float4*)&xs[nl][k];
        float4 b = *(const float4*)&ws[q][k];
        acc += a.x * b.x + a.y * b.y + a.z * b.z + a.w * b.w;
    }
    int n = n0 + nl;
    if (n < N_NODES) {
        int r = q >> 1;
        if ((q & 1) == 0) Dn[n * 8 + r] = acc;
        else              Sr[n * 8 + r] = acc;
    }
}

// ---------------------------------------------------------------------------
// K2: XCD-partitioned ELL scatter, 1 edge/thread (R2 structure, confirmed
// 47.8us). R4 change vs R2: cnt is UNPADDED (CPAD 16->1). The 64B-per-
// counter padding made the atomic working set 3.2MB; per-XCD slice fought
// the edge stream for L2 and each atomic miss pulled+dirtied a full line
// (up to ~50MB fetch+writeback -- same order as the whole measured FETCH).
// Unpadded cnt = 200KB total, 25KB/XCD slice: always L2-resident, atomics
// combine in place. Same-line contention is rare (8 live lanes/wave over
// 3125 lines) and TCC atomics to distinct offsets don't serialize.
// R3's nt hints REVERTED (raised load latency, didn't cut churn).
// ---------------------------------------------------------------------------
__global__ __launch_bounds__(256) void scatter_kernel(
    const int* __restrict__ src, const int* __restrict__ dst,
    const int* __restrict__ rel,
    int* __restrict__ cnt,
    const float* __restrict__ Dn, const float* __restrict__ Sr,
    unsigned int* __restrict__ epack) {
    int seg   = blockIdx.x & (NSEG - 1);
    int chunk = blockIdx.x >> 3;
    int e = chunk * 256 + threadIdx.x;
    if (e >= N_EDGES) return;

    // issue all three coalesced loads before any dependent use
    int d = dst[e];
    int s = src[e];
    int r = rel[e];
    // pin: forbid sinking src/rel loads into the survivor branch
    asm volatile("" :: "v"(d), "v"(s), "v"(r));

    if ((unsigned)d / SEG_DIV != (unsigned)seg) return;   // magic-mul div

    // rank is independent of gate: issue the atomic first, overlap gathers
    int rank = atomicAdd(&cnt[d], 1);

    float logit = Dn[d * 8 + r] + Sr[s * 8 + r];
    float gate = 1.0f / (1.0f + __expf(-logit));
    if (rank < MAXDEG) {
        unsigned pv = ((unsigned)__half_as_ushort(__float2half_rn(gate)) << 16)
                    | (unsigned)s;
        epack[(size_t)d * MAXDEG + rank] = pv;
    }
}

// ---------------------------------------------------------------------------
// K3: aggregation over ELL rows (R3 wave-load + shfl structure, kept).
// Whole ELL row (<=64 slots) read as one lane-coalesced wave load; (gate,src)
// distributed by __shfl so all xb gathers are independent (wave-level MLP),
// no branches (pad slots carry gate=0/src=0).
// ---------------------------------------------------------------------------
__global__ __launch_bounds__(256) void agg_kernel(
    const unsigned short* __restrict__ xb,
    const int*   __restrict__ cnt,
    const unsigned int* __restrict__ epack,
    unsigned int* __restrict__ aggb)   // (N_NODES, 32) packed bf16 pairs
{
    int n    = (blockIdx.x * blockDim.x + threadIdx.x) >> 6;
    int lane = threadIdx.x & 63;
    if (n >= N_NODES) return;

    int deg = cnt[n];
    int m   = (deg < MAXDEG) ? deg : MAXDEG;

    // one coalesced read of the whole ELL row: lane l <- slot l
    unsigned ev = 0u;
    if (lane < m) ev = epack[(size_t)n * MAXDEG + lane];
    float gl = __half2float(__ushort_as_half((unsigned short)(ev >> 16)));
    int   ol = (int)(ev & 0xFFFFu) * D;   // element offset of src row

    int sub = lane >> 4;       // edge slot group 0..3
    int q4  = (lane & 15) * 4; // dims q4..q4+3

    float ax = 0.f, ay = 0.f, az = 0.f, aw = 0.f;

    for (int base = 0; base < m; base += 8) {
        int e0 = base + sub;
        int e1 = base + 4 + sub;
        float g0 = __shfl(gl, e0, 64);
        int   o0 = __shfl(ol, e0, 64);
        float g1 = __shfl(gl, e1, 64);
        int   o1 = __shfl(ol, e1, 64);
        uint2 u0 = *(const uint2*)&xb[(size_t)o0 + q4];
        uint2 u1 = *(const uint2*)&xb[(size_t)o1 + q4];
        ax += g0 * BFLO(u0.x) + g1 * BFLO(u1.x);
        ay += g0 * BFHI(u0.x) + g1 * BFHI(u1.x);
        az += g0 * BFLO(u0.y) + g1 * BFLO(u1.y);
        aw += g0 * BFHI(u0.y) + g1 * BFHI(u1.y);
    }

#pragma unroll
    for (int off = 16; off <= 32; off <<= 1) {
        ax += __shfl_xor(ax, off, 64);
        ay += __shfl_xor(ay, off, 64);
        az += __shfl_xor(az, off, 64);
        aw += __shfl_xor(aw, off, 64);
    }

    if (sub == 0) {
        float inv = 1.0f / fmaxf((float)deg, 1.0f);   // normalize by TRUE degree
        uint2 pr;
        pr.x = f2bf(ax * inv) | (f2bf(ay * inv) << 16);
        pr.y = f2bf(az * inv) | (f2bf(aw * inv) << 16);
        *(uint2*)&aggb[(size_t)n * 32 + 2 * (lane & 15)] = pr;
    }
}

// ---------------------------------------------------------------------------
// K4: out = leaky_relu([x, agg] @ W_lin^T + b), all LDS operands bf16-packed.
// ---------------------------------------------------------------------------
__global__ __launch_bounds__(256, 6) void lin_kernel(
    const unsigned int* __restrict__ xbu,   // packed x, 32 uints/node
    const unsigned int* __restrict__ aggb,  // packed agg, 32 uints/node
    const float* __restrict__ W_lin,
    const float* __restrict__ b_lin,
    float* __restrict__ out)
{
    __shared__ unsigned int W2[64][66];
    __shared__ unsigned int c2[NODES_PER_BLK][66];
    __shared__ float b_lds[64];

    int tid = threadIdx.x;
    int n0  = blockIdx.x * NODES_PER_BLK;

    for (int i = tid; i < 64 * 64; i += 256) {
        int j = i >> 6, kp = i & 63;
        float2 wv = *(const float2*)&W_lin[j * 128 + kp * 2];
        W2[j][kp] = f2bf(wv.x) | (f2bf(wv.y) << 16);
    }
    if (tid < 64) b_lds[tid] = b_lin[tid];

    for (int i = tid; i < NODES_PER_BLK * 32; i += 256) {
        int nl = i >> 5, kp = i & 31;
        int n  = n0 + nl;
        unsigned vx = 0u, va = 0u;
        if (n < N_NODES) {
            vx = xbu[(size_t)n * 32 + kp];
            va = aggb[(size_t)n * 32 + kp];
        }
        c2[nl][kp]      = vx;
        c2[nl][32 + kp] = va;
    }
    __syncthreads();

    int tx = tid & 15, ty = tid >> 4;
    float acc[2][4];
#pragma unroll
    for (int i = 0; i < 2; ++i)
#pragma unroll
        for (int jj = 0; jj < 4; ++jj) acc[i][jj] = b_lds[tx + 16 * jj];

#pragma unroll 2
    for (int kp = 0; kp < 64; kp += 2) {      // 2 pairs = 4 dims per iter
        uint2 cu[2], wu[4];
        cu[0] = *(const uint2*)&c2[ty][kp];
        cu[1] = *(const uint2*)&c2[ty + 16][kp];
#pragma unroll
        for (int jj = 0; jj < 4; ++jj)
            wu[jj] = *(const uint2*)&W2[tx + 16 * jj][kp];
#pragma unroll
        for (int i = 0; i < 2; ++i) {
            float cx = BFLO(cu[i].x), cy = BFHI(cu[i].x);
            float cz = BFLO(cu[i].y), cw = BFHI(cu[i].y);
#pragma unroll
            for (int jj = 0; jj < 4; ++jj) {
                acc[i][jj] += cx * BFLO(wu[jj].x) + cy * BFHI(wu[jj].x)
                            + cz * BFLO(wu[jj].y) + cw * BFHI(wu[jj].y);
            }
        }
    }

#pragma unroll
    for (int i = 0; i < 2; ++i) {
        int n = n0 + ty + 16 * i;
        if (n < N_NODES) {
#pragma unroll
            for (int jj = 0; jj < 4; ++jj) {
                float v = acc[i][jj];
                out[(size_t)n * D + tx + 16 * jj] = (v > 0.f) ? v : 0.01f * v;
            }
        }
    }
}

// ---------------------------------------------------------------------------
extern "C" void kernel_launch(void* const* d_in, const int* in_sizes, int n_in,
                              void* d_out, int out_size, void* d_ws, size_t ws_size,
                              hipStream_t stream) {
    const float* x     = (const float*)d_in[0];
    const int*   src   = (const int*)  d_in[1];
    const int*   dst   = (const int*)  d_in[2];
    const int*   rel   = (const int*)  d_in[3];
    const float* W_r   = (const float*)d_in[4];
    const float* W_lin = (const float*)d_in[5];
    const float* b_lin = (const float*)d_in[6];
    float* out = (float*)d_out;

    char* p = (char*)d_ws;
    float*  w       = (float*)p;                p += 4096;
    float*  Dn      = (float*)p;                p += (size_t)N_NODES * 8 * 4;       // 1.6 MB
    float*  Sr      = (float*)p;                p += (size_t)N_NODES * 8 * 4;       // 1.6 MB
    int*    cnt     = (int*)p;                  p += 256 * 1024;                    // 200 KB used
    unsigned int* epack = (unsigned int*)p;     p += (size_t)N_NODES * MAXDEG * 4;  // 12.8 MB
    unsigned short* xb = (unsigned short*)p;    p += (size_t)N_NODES * D * 2;       // 6.4 MB
    unsigned int* aggb = (unsigned int*)p;      p += (size_t)N_NODES * 32 * 4;      // 6.4 MB

    wprep_kernel<<<512, 256, 0, stream>>>(W_r, w, cnt);
    tables_kernel<<<(N_NODES + TN - 1) / TN, 256, 0, stream>>>(x, w, Dn, Sr, xb);
    scatter_kernel<<<NSEG * ((N_EDGES + 255) / 256), 256, 0, stream>>>(
        src, dst, rel, cnt, Dn, Sr, epack);
    agg_kernel<<<(N_NODES * 64 + 255) / 256, 256, 0, stream>>>(xb, cnt, epack, aggb);
    lin_kernel<<<(N_NODES + NODES_PER_BLK - 1) / NODES_PER_BLK, 256, 0, stream>>>(
        (const unsigned int*)xb, aggb, W_lin, b_lin, out);
}